// Round 17
// baseline (40.417 us; speedup 1.0000x reference)
//
#include <hip/hip_runtime.h>
#include <stdint.h>

#define D_DIM 256
#define K_CTR 1024
#define B_ROWS 16384
#define BM 32

typedef float f32x4 __attribute__((ext_vector_type(4)));
typedef float f32x2 __attribute__((ext_vector_type(2)));
typedef long long i64x2 __attribute__((ext_vector_type(2)));

// Pack 4 f32 -> 4 fp8 e4m3 bytes (OCP, HW cvt).
static __device__ __forceinline__ unsigned cvt4_fp8(const float4 v) {
    int r = __builtin_amdgcn_cvt_pk_fp8_f32(v.x, v.y, 0, false);   // bytes 0-1
    r = __builtin_amdgcn_cvt_pk_fp8_f32(v.z, v.w, r, true);        // bytes 2-3
    return (unsigned)r;
}

// lgkm-only barrier: LDS handoffs need lgkmcnt(0)+s_barrier; global stores/loads
// stay in flight across it and drain under subsequent compute.
static __device__ __forceinline__ void barrier_lgkm() {
    asm volatile("s_waitcnt lgkmcnt(0)" ::: "memory");
    __builtin_amdgcn_s_barrier();
}

// Prep: centers f32 -> fp8 fragment-major (pair-interleaved) + c_sq f32.
// Value c[col][d] (kk=d>>5, p=kk>>1, e=kk&1, hk=(d>>3)&3, j=d&7) at byte:
//   (col>>4)*4096 + p*1024 + (hk*16 + (col&15))*16 + e*8 + j
// -> main's wave load (lane l) at p*1024 + l*16 is one 1KB dwordx4 holding
//    frags kk=2p (bytes 0-7) and kk=2p+1 (bytes 8-15).
__global__ __launch_bounds__(256) void rbf_prep(const float* __restrict__ centers,
                                                unsigned char* __restrict__ cbf,
                                                float* __restrict__ csq) {
    const int w = threadIdx.x >> 6;
    const int l = threadIdx.x & 63;
    const int c0 = blockIdx.x * 4 + w;
    const float4 v = *reinterpret_cast<const float4*>(centers + c0 * D_DIM + l * 4);
    float s = v.x * v.x + v.y * v.y + v.z * v.z + v.w * v.w;
    const unsigned u = cvt4_fp8(v);
    const unsigned off = (unsigned)((c0 >> 4) * 4096 + (l >> 4) * 1024
                       + (((l >> 1) & 3) * 16 + (c0 & 15)) * 16
                       + ((l >> 3) & 1) * 8 + (l & 1) * 4);
    *reinterpret_cast<unsigned*>(cbf + off) = u;
    #pragma unroll
    for (int off2 = 1; off2 < 64; off2 <<= 1) s += __shfl_xor(s, off2);
    if (l == 0) csq[c0] = s;
}

// Main: 512 thr (8 waves), block = 32 rows x 512 cols (col-split 2), grid 1024.
// R11 machinery exactly, 4 phases of 128 cols per block. launch_bounds(512,6)
// + 40.6KB LDS -> up to 3 blocks co-resident per CU, grid > capacity -> block
// REFILL: later blocks' latency-bound prologues (x loads, cvt, LDS handoff)
// hide under earlier blocks' compute/stores instead of being exposed at t=0.
__global__ __launch_bounds__(512, 6) void rbf_main(const float* __restrict__ x,
                                                   const unsigned char* __restrict__ cbf,
                                                   const float* __restrict__ csq,
                                                   const float* __restrict__ betas,
                                                   float* __restrict__ out) {
    __shared__ __align__(16) unsigned char As[BM * D_DIM];   // 8 KB fp8, swizzled
    __shared__ __align__(16) float obuf[2][BM * 128];        // 2 x 16 KB, swizzled
    __shared__ float xs_lds[BM];

    const int tid = threadIdx.x;
    const int w = tid >> 6;
    const int l = tid & 63;
    // XCD-chunked bijective swizzle over 1024 blocks: XCDs 0-3 -> col half 0
    // (cbf bytes 0..128K hot in their L2), XCDs 4-7 -> col half 1.
    const int swz = (blockIdx.x & 7) * 128 + (blockIdx.x >> 3);
    const int strip = swz & 511;
    const int cidx  = swz >> 9;              // 0/1 -> column half
    const int row0 = strip * BM;

    // ---- Stage A strip as fp8 (swizzled) + x_sq ----
    #pragma unroll
    for (int i = 0; i < 4; ++i) {
        const int r = i * 8 + w;
        const float4 v = *reinterpret_cast<const float4*>(x + (size_t)(row0 + r) * D_DIM + l * 4);
        float s = v.x * v.x + v.y * v.y + v.z * v.z + v.w * v.w;
        const unsigned u = cvt4_fp8(v);
        const unsigned pos = (unsigned)((l >> 4) * 64 + ((l >> 1) & 3) * 16
                           + ((l >> 3) & 1) * 8 + (l & 1) * 4);
        *reinterpret_cast<unsigned*>(As + r * 256 + (pos ^ ((unsigned)(r & 7) << 4))) = u;
        #pragma unroll
        for (int off = 1; off < 64; off <<= 1) s += __shfl_xor(s, off);
        if (l == 0) xs_lds[r] = s;
    }

    const int hk = l >> 4;
    const int lr = l & 15;
    const unsigned char* bwave = cbf + l * 16;
    const int cgbase = cidx * 32;            // this block's first colgroup

    // ---- Issue B(phase 0) BEFORE the barrier (stays in flight across it) ----
    i64x2 b0[4], b1[4];
    {
        const unsigned char* bbase = bwave + (cgbase + w) * 4096;
        #pragma unroll
        for (int p = 0; p < 4; ++p)
            b0[p] = *reinterpret_cast<const i64x2*>(bbase + p * 1024);
    }
    barrier_lgkm();   // As + xs_lds handoff (LDS-only)

    // ---- Hoist A frags once: 8 ds_read_b128 ----
    i64x2 a[2][4];
    #pragma unroll
    for (int m = 0; m < 2; ++m) {
        const int r = m * 16 + lr;
        #pragma unroll
        for (int p = 0; p < 4; ++p)
            a[m][p] = *reinterpret_cast<const i64x2*>(
                As + r * 256 + ((unsigned)(p * 64 + hk * 16) ^ ((unsigned)(lr & 7) << 4)));
    }
    const float xs0 = xs_lds[lr];
    const float xs1 = xs_lds[16 + lr];
    const float LOG2E = 1.4426950408889634f;

    #pragma unroll
    for (int ph = 0; ph < 4; ++ph) {
        const int colp = cidx * 512 + ph * 128;        // absolute phase col base
        const i64x2 (&bc)[4] = (ph & 1) ? b1 : b0;
        i64x2 (&bn)[4] = (ph & 1) ? b0 : b1;

        // ---- Prefetch B(ph+1): colgroup cgbase + (ph+1)*8 + w ----
        if (ph < 3) {
            const unsigned char* bbase = bwave + (cgbase + (ph + 1) * 8 + w) * 4096;
            #pragma unroll
            for (int p = 0; p < 4; ++p)
                bn[p] = *reinterpret_cast<const i64x2*>(bbase + p * 1024);
        }

        // ---- 16 MFMAs, 2 independent acc chains ----
        f32x4 acc[2] = {};
        #pragma unroll
        for (int p = 0; p < 4; ++p)
            #pragma unroll
            for (int m = 0; m < 2; ++m) {
                acc[m] = __builtin_amdgcn_mfma_f32_16x16x32_fp8_fp8(bc[p][0], a[m][p][0], acc[m], 0, 0, 0);
                acc[m] = __builtin_amdgcn_mfma_f32_16x16x32_fp8_fp8(bc[p][1], a[m][p][1], acc[m], 0, 0, 0);
            }

        // ---- Epilogue: exp2(fma(2*bt*log2e, acc, -bt*log2e*(xs+cs))) -> obuf ----
        float* ob = obuf[ph & 1];
        {
            const int cl = w * 16 + hk * 4;            // col within 128-col phase
            const f32x4 cs = *reinterpret_cast<const f32x4*>(csq + colp + cl);
            const f32x4 bt = *reinterpret_cast<const f32x4*>(betas + colp + cl);
            #pragma unroll
            for (int m = 0; m < 2; ++m) {
                const int r = m * 16 + lr;
                const float xsv = m ? xs1 : xs0;
                f32x4 rv;
                #pragma unroll
                for (int j = 0; j < 4; ++j) {
                    const float btl2 = bt[j] * LOG2E;
                    const float cc = -btl2 * (xsv + cs[j]);
                    rv[j] = __builtin_exp2f(__builtin_fmaf(btl2 + btl2, acc[m][j], cc));
                }
                *reinterpret_cast<f32x4*>(reinterpret_cast<char*>(ob)
                    + r * 512 + ((unsigned)(cl * 4) ^ ((unsigned)(r & 7) << 4))) = rv;
            }
        }
        barrier_lgkm();   // obuf handoff (LDS-only; global stores keep flowing)

        // ---- Stores: wave w -> rows 4w..4w+3; each instr = ONE 512B segment ----
        #pragma unroll
        for (int i = 0; i < 4; ++i) {
            const int r = w * 4 + i;
            const f32x2 v = *reinterpret_cast<const f32x2*>(reinterpret_cast<const char*>(obuf[ph & 1])
                    + r * 512 + ((unsigned)(l * 8) ^ ((unsigned)(r & 7) << 4)));
            *reinterpret_cast<f32x2*>(out + (size_t)(row0 + r) * K_CTR + colp + l * 2) = v;
        }
        // obuf[ph&1] is rewritten at ph+2, after barrier(ph+1): every wave's
        // ph-store ds_reads completed (lgkmcnt(0)) before crossing that barrier.
    }
}

extern "C" void kernel_launch(void* const* d_in, const int* in_sizes, int n_in,
                              void* d_out, int out_size, void* d_ws, size_t ws_size,
                              hipStream_t stream) {
    const float* x       = (const float*)d_in[0];
    const float* centers = (const float*)d_in[1];
    const float* betas   = (const float*)d_in[2];
    float* out = (float*)d_out;

    unsigned char* cbf = (unsigned char*)d_ws;                        // 256 KB fp8 fragment-major centers
    float* csq = (float*)((char*)d_ws + (size_t)K_CTR * D_DIM);       // 4 KB c_sq

    rbf_prep<<<K_CTR / 4, 256, 0, stream>>>(centers, cbf, csq);
    rbf_main<<<(B_ROWS / BM) * 2, 512, 0, stream>>>(x, cbf, csq, betas, out);
}

// Round 18
// 26.505 us; speedup vs baseline: 1.5249x; 1.5249x over previous
//
#include <hip/hip_runtime.h>
#include <stdint.h>

#define D_DIM 256
#define K_CTR 1024
#define B_ROWS 16384
#define BM 32
#define NSTRIP (B_ROWS / BM)   // 512

typedef float f32x4 __attribute__((ext_vector_type(4)));
typedef float f32x2 __attribute__((ext_vector_type(2)));
typedef long long i64x2 __attribute__((ext_vector_type(2)));
typedef unsigned int u32x4 __attribute__((ext_vector_type(4)));

// Pack 4 f32 -> 4 fp8 e4m3 bytes (OCP, HW cvt).
static __device__ __forceinline__ unsigned cvt4_fp8(const float4 v) {
    int r = __builtin_amdgcn_cvt_pk_fp8_f32(v.x, v.y, 0, false);   // bytes 0-1
    r = __builtin_amdgcn_cvt_pk_fp8_f32(v.z, v.w, r, true);        // bytes 2-3
    return (unsigned)r;
}

// lgkm-only barrier: LDS handoffs need lgkmcnt(0)+s_barrier; global stores/loads
// stay in flight across it and drain under subsequent compute.
static __device__ __forceinline__ void barrier_lgkm() {
    asm volatile("s_waitcnt lgkmcnt(0)" ::: "memory");
    __builtin_amdgcn_s_barrier();
}

// Lane-l position within a row's 256B fragment image (d = 4l..4l+3):
// pos = p*64 + hk*16 + e*8 + j with p=l>>4, hk=(l>>1)&3, e=(l>>3)&1, j=(l&1)*4.
static __device__ __forceinline__ unsigned lane_pos(int l) {
    return (unsigned)((l >> 4) * 64 + ((l >> 1) & 3) * 16 + ((l >> 3) & 1) * 8 + (l & 1) * 4);
}

// Prep v2: (a) blocks 0..2047: x -> fp8 pre-swizzled As-image (xb, 4MB) + xsq;
//          (b) blocks 2048..2303: centers -> fp8 fragment-major cbf + csq.
// cbf layout: value c[col][d] at byte (col>>4)*4096 + p*1024 + (hk*16+(col&15))*16
// + e*8 + j  -> main's wave B-load (lane l) at p*1024 + l*16 is one 1KB dwordx4.
// xb layout: strip s, row r (0..31), byte = s*8192 + r*256 + (lane_pos ^ ((r&7)<<4))
// == exactly the LDS As image main used to build; main now just copies it in.
__global__ __launch_bounds__(256) void rbf_prep(const float* __restrict__ x,
                                                const float* __restrict__ centers,
                                                unsigned char* __restrict__ cbf,
                                                float* __restrict__ csq,
                                                unsigned char* __restrict__ xb,
                                                float* __restrict__ xsq) {
    const int w = threadIdx.x >> 6;
    const int l = threadIdx.x & 63;
    if (blockIdx.x < 2048) {
        // ---- x: 8 rows per block ----
        #pragma unroll
        for (int i = 0; i < 2; ++i) {
            const int row = blockIdx.x * 8 + i * 4 + w;
            const float4 v = *reinterpret_cast<const float4*>(x + (size_t)row * D_DIM + l * 4);
            float s = v.x * v.x + v.y * v.y + v.z * v.z + v.w * v.w;
            const unsigned u = cvt4_fp8(v);
            const int strip = row >> 5, rloc = row & 31;
            *reinterpret_cast<unsigned*>(xb + (size_t)strip * 8192 + rloc * 256
                + (lane_pos(l) ^ ((unsigned)(rloc & 7) << 4))) = u;
            #pragma unroll
            for (int off = 1; off < 64; off <<= 1) s += __shfl_xor(s, off);
            if (l == 0) xsq[row] = s;
        }
    } else {
        // ---- centers: 4 cols per block ----
        const int c0 = (blockIdx.x - 2048) * 4 + w;
        const float4 v = *reinterpret_cast<const float4*>(centers + c0 * D_DIM + l * 4);
        float s = v.x * v.x + v.y * v.y + v.z * v.z + v.w * v.w;
        const unsigned u = cvt4_fp8(v);
        const unsigned off = (unsigned)((c0 >> 4) * 4096 + (l >> 4) * 1024
                           + (((l >> 1) & 3) * 16 + (c0 & 15)) * 16
                           + ((l >> 3) & 1) * 8 + (l & 1) * 4);
        *reinterpret_cast<unsigned*>(cbf + off) = u;
        #pragma unroll
        for (int off2 = 1; off2 < 64; off2 <<= 1) s += __shfl_xor(s, off2);
        if (l == 0) csq[c0] = s;
    }
}

// Main: 512 thr (8 waves), block = 32 rows x 1024 cols, 8 phases of 128 cols
// (R11 machinery). Prologue is now a straight 8KB copy of the precomputed
// As-image (one dwordx4 + ds_write_b128 per thread). Store sources ping-pong
// between two register sets with an asm keepalive so a store's data registers
// are never reused until >=1 full phase later (store-data hazard never waits
// on the backpressured L2 write queue).
__global__ __launch_bounds__(512, 4) void rbf_main(const unsigned char* __restrict__ xb,
                                                   const float* __restrict__ xsq,
                                                   const unsigned char* __restrict__ cbf,
                                                   const float* __restrict__ csq,
                                                   const float* __restrict__ betas,
                                                   float* __restrict__ out) {
    __shared__ __align__(16) unsigned char As[BM * D_DIM];   // 8 KB fp8 image
    __shared__ __align__(16) float obuf[2][BM * 128];        // 2 x 16 KB, swizzled

    const int tid = threadIdx.x;
    const int w = tid >> 6;
    const int l = tid & 63;
    // XCD-chunked bijective swizzle (512 = 8*64)
    const int strip = (blockIdx.x & 7) * 64 + (blockIdx.x >> 3);
    const int row0 = strip * BM;

    // ---- Prologue: copy precomputed As image (8 KB) into LDS ----
    {
        const u32x4 v = *reinterpret_cast<const u32x4*>(xb + (size_t)strip * 8192 + tid * 16);
        *reinterpret_cast<u32x4*>(As + tid * 16) = v;
    }

    const int hk = l >> 4;
    const int lr = l & 15;
    const unsigned char* bwave = cbf + l * 16;

    // ---- Issue B(phase 0) BEFORE the barrier (stays in flight across it) ----
    i64x2 b0[4], b1[4];
    {
        const unsigned char* bbase = bwave + w * 4096;
        #pragma unroll
        for (int p = 0; p < 4; ++p)
            b0[p] = *reinterpret_cast<const i64x2*>(bbase + p * 1024);
    }
    barrier_lgkm();   // As handoff (ds_write tracked by lgkm; vmcnt auto-waited pre-ds_write)

    // ---- Hoist A frags once: 8 ds_read_b128 ----
    i64x2 a[2][4];
    #pragma unroll
    for (int m = 0; m < 2; ++m) {
        const int r = m * 16 + lr;
        #pragma unroll
        for (int p = 0; p < 4; ++p)
            a[m][p] = *reinterpret_cast<const i64x2*>(
                As + r * 256 + ((unsigned)(p * 64 + hk * 16) ^ ((unsigned)(lr & 7) << 4)));
    }
    const float xs0 = xsq[row0 + lr];
    const float xs1 = xsq[row0 + 16 + lr];
    const float LOG2E = 1.4426950408889634f;

    // Store-source register ping-pong (overwritten only one full phase later).
    f32x2 svA[4] = {}, svB[4] = {};

    #pragma unroll
    for (int ph = 0; ph < 8; ++ph) {
        const int colp = ph * 128;
        const i64x2 (&bc)[4] = (ph & 1) ? b1 : b0;
        i64x2 (&bn)[4] = (ph & 1) ? b0 : b1;

        // ---- Prefetch B(ph+1) ----
        if (ph < 7) {
            const unsigned char* bbase = bwave + ((ph + 1) * 8 + w) * 4096;
            #pragma unroll
            for (int p = 0; p < 4; ++p)
                bn[p] = *reinterpret_cast<const i64x2*>(bbase + p * 1024);
        }

        // ---- 16 MFMAs, 2 independent acc chains ----
        f32x4 acc[2] = {};
        #pragma unroll
        for (int p = 0; p < 4; ++p)
            #pragma unroll
            for (int m = 0; m < 2; ++m) {
                acc[m] = __builtin_amdgcn_mfma_f32_16x16x32_fp8_fp8(bc[p][0], a[m][p][0], acc[m], 0, 0, 0);
                acc[m] = __builtin_amdgcn_mfma_f32_16x16x32_fp8_fp8(bc[p][1], a[m][p][1], acc[m], 0, 0, 0);
            }

        // ---- Epilogue: exp2(fma(2*bt*log2e, acc, -bt*log2e*(xs+cs))) -> obuf ----
        float* ob = obuf[ph & 1];
        {
            const int cl = w * 16 + hk * 4;        // col within 128-col phase
            const f32x4 cs = *reinterpret_cast<const f32x4*>(csq + colp + cl);
            const f32x4 bt = *reinterpret_cast<const f32x4*>(betas + colp + cl);
            #pragma unroll
            for (int m = 0; m < 2; ++m) {
                const int r = m * 16 + lr;
                const float xsv = m ? xs1 : xs0;
                f32x4 rv;
                #pragma unroll
                for (int j = 0; j < 4; ++j) {
                    const float btl2 = bt[j] * LOG2E;
                    const float cc = -btl2 * (xsv + cs[j]);
                    rv[j] = __builtin_exp2f(__builtin_fmaf(btl2 + btl2, acc[m][j], cc));
                }
                *reinterpret_cast<f32x4*>(reinterpret_cast<char*>(ob)
                    + r * 512 + ((unsigned)(cl * 4) ^ ((unsigned)(r & 7) << 4))) = rv;
            }
        }
        barrier_lgkm();   // obuf handoff (LDS-only; global stores keep flowing)

        // ---- Stores: wave w -> rows 4w..4w+3; ONE 512B segment per instr.
        //      sv parity alternates; keepalive pins the OTHER parity's regs so
        //      last phase's store data is never overwritten while in flight.
        f32x2 (&sv)[4]  = (ph & 1) ? svB : svA;
        f32x2 (&svo)[4] = (ph & 1) ? svA : svB;
        asm volatile("" :: "v"(svo[0]), "v"(svo[1]), "v"(svo[2]), "v"(svo[3]));
        #pragma unroll
        for (int i = 0; i < 4; ++i) {
            const int r = w * 4 + i;
            sv[i] = *reinterpret_cast<const f32x2*>(reinterpret_cast<const char*>(obuf[ph & 1])
                    + r * 512 + ((unsigned)(l * 8) ^ ((unsigned)(r & 7) << 4)));
        }
        #pragma unroll
        for (int i = 0; i < 4; ++i) {
            const int r = w * 4 + i;
            *reinterpret_cast<f32x2*>(out + (size_t)(row0 + r) * K_CTR + colp + l * 2) = sv[i];
        }
        // obuf[ph&1] rewritten at ph+2, after barrier(ph+1): every wave's
        // ph-store ds_reads completed (lgkmcnt(0)) before crossing that barrier.
    }
}

extern "C" void kernel_launch(void* const* d_in, const int* in_sizes, int n_in,
                              void* d_out, int out_size, void* d_ws, size_t ws_size,
                              hipStream_t stream) {
    const float* x       = (const float*)d_in[0];
    const float* centers = (const float*)d_in[1];
    const float* betas   = (const float*)d_in[2];
    float* out = (float*)d_out;

    unsigned char* cbf = (unsigned char*)d_ws;                        // 256 KB fp8 fragment-major centers
    float* csq = (float*)((char*)d_ws + 262144);                      // 4 KB c_sq
    unsigned char* xb  = (unsigned char*)d_ws + 262144 + 4096;        // 4 MB fp8 As-images
    float* xsq = (float*)((char*)d_ws + 262144 + 4096 + (size_t)NSTRIP * 8192);   // 64 KB x_sq

    rbf_prep<<<2048 + K_CTR / 4, 256, 0, stream>>>(x, centers, cbf, csq, xb, xsq);
    rbf_main<<<NSTRIP, 512, 0, stream>>>(xb, xsq, cbf, csq, betas, out);
}